// Round 1
// baseline (754.049 us; speedup 1.0000x reference)
//
#include <hip/hip_runtime.h>
#include <stdint.h>

#define TOKENS 2048
#define HIDDEN 2048
#define INTER  1408
#define NEXP   16
#define LDA    40   // LDS row stride in ushorts (32 + 8 pad, keeps 16B alignment)

using bf16x8 = __attribute__((ext_vector_type(8))) __bf16;
using f32x4  = __attribute__((ext_vector_type(4))) float;

__device__ __forceinline__ unsigned int bfround(float f) {
    union { float f; unsigned int u; } a; a.f = f;
    return (a.u + 0x7fffu + ((a.u >> 16) & 1u)) >> 16;   // RNE fp32->bf16
}
__device__ __forceinline__ unsigned int pack2(float a, float b) {
    return bfround(a) | (bfround(b) << 16);
}

// ---------------- router: logits -> sigmoid -> top2 -> expert lists ----------------
__global__ __launch_bounds__(64) void router_kernel(
    const float* __restrict__ x, const float* __restrict__ wg,
    int* __restrict__ cnt, int* __restrict__ tok, float* __restrict__ wts)
{
    const int t = blockIdx.x;
    const int lane = threadIdx.x;
    float acc[NEXP];
#pragma unroll
    for (int e = 0; e < NEXP; e++) acc[e] = 0.f;
    const float* xr = x + (size_t)t * HIDDEN;
    for (int h = lane; h < HIDDEN; h += 64) {
        const float xv = xr[h];
        const float* wr = wg + (size_t)h * NEXP;
#pragma unroll
        for (int e = 0; e < NEXP; e++) acc[e] += xv * wr[e];
    }
#pragma unroll
    for (int off = 32; off > 0; off >>= 1) {
#pragma unroll
        for (int e = 0; e < NEXP; e++) acc[e] += __shfl_down(acc[e], off, 64);
    }
    if (lane == 0) {
        float s[NEXP];
#pragma unroll
        for (int e = 0; e < NEXP; e++) s[e] = 1.f / (1.f + __expf(-acc[e]));
        int i0 = 0;
#pragma unroll
        for (int e = 1; e < NEXP; e++) if (s[e] > s[i0]) i0 = e;
        int i1 = (i0 == 0) ? 1 : 0;
#pragma unroll
        for (int e = 0; e < NEXP; e++) if (e != i0 && s[e] > s[i1]) i1 = e;
        float w0 = s[i0], w1 = s[i1];
        const float inv = 1.f / (w0 + w1);
        w0 *= inv; w1 *= inv;
        const int s0 = atomicAdd(&cnt[i0], 1);
        tok[i0 * TOKENS + s0] = t * 2;
        wts[i0 * TOKENS + s0] = w0;
        const int s1 = atomicAdd(&cnt[i1], 1);
        tok[i1 * TOKENS + s1] = t * 2 + 1;
        wts[i1 * TOKENS + s1] = w1;
    }
}

// ---------------- gemm1: h = silu(Xe @ Wg) * (Xe @ Wu), bf16 out ----------------
// grid: (INTER/64, TOKENS/128, NEXP), block 256
__global__ __launch_bounds__(256) void gemm1_kernel(
    const float* __restrict__ x, const float* __restrict__ wgp,
    const float* __restrict__ wup, const int* __restrict__ cnt,
    const int* __restrict__ tok, unsigned short* __restrict__ hbuf)
{
    const int e = blockIdx.z;
    const int ne = cnt[e];
    const int m0 = blockIdx.y * 128;
    if (m0 >= ne) return;
    const int n0 = blockIdx.x * 64;

    __shared__ __align__(16) unsigned short As[128][LDA];
    __shared__ __align__(16) unsigned short Bs[2][64][LDA];
    __shared__ int rowp[128];

    const int tid = threadIdx.x;
    if (tid < 128) {
        const int slot = m0 + tid;
        const int cs = slot < ne ? slot : ne - 1;
        rowp[tid] = tok[e * TOKENS + cs];
    }
    __syncthreads();

    const int lane = tid & 63;
    const int wid  = tid >> 6;
    const int wm = (wid >> 1) * 64;
    const int wn = (wid & 1) * 32;
    const int lr = lane & 15;
    const int lq = lane >> 4;

    f32x4 accg[4][2], accu[4][2];
    const f32x4 z4 = {0.f, 0.f, 0.f, 0.f};
#pragma unroll
    for (int a = 0; a < 4; a++)
#pragma unroll
        for (int b = 0; b < 2; b++) { accg[a][b] = z4; accu[a][b] = z4; }

    const size_t wbase = (size_t)e * HIDDEN * INTER + n0;
    const float* wgq = wgp + wbase;
    const float* wuq = wup + wbase;

    const int arow = tid >> 3;        // 0..31
    const int acol = (tid & 7) * 4;   // 0..28
    int atok[4];
#pragma unroll
    for (int i = 0; i < 4; i++) atok[i] = rowp[arow + i * 32] >> 1;

    for (int k0 = 0; k0 < HIDDEN; k0 += 32) {
        // stage A tile (128x32 fp32 -> bf16), gathered token rows
#pragma unroll
        for (int i = 0; i < 4; i++) {
            const float4 v = *(const float4*)(x + (size_t)atok[i] * HIDDEN + k0 + acol);
            uint2 pv; pv.x = pack2(v.x, v.y); pv.y = pack2(v.z, v.w);
            *(uint2*)&As[arow + i * 32][acol] = pv;
        }
        // stage B tiles (gate & up), transposed to [n][k] so fragments are contiguous
#pragma unroll
        for (int i = 0; i < 4; i++) {
            const int sel = i >> 1;
            const int rem = ((i & 1) << 8) + tid;
            const int kg = rem >> 6;   // 0..7 (4 k's each)
            const int n  = rem & 63;
            const float* src = (sel ? wuq : wgq) + (size_t)(k0 + kg * 4) * INTER + n;
            uint2 pv;
            pv.x = pack2(src[0], src[(size_t)INTER]);
            pv.y = pack2(src[2 * (size_t)INTER], src[3 * (size_t)INTER]);
            *(uint2*)&Bs[sel][n][kg * 4] = pv;
        }
        __syncthreads();

        bf16x8 af[4], bg[2], bu[2];
#pragma unroll
        for (int tm = 0; tm < 4; tm++)
            af[tm] = *(const bf16x8*)&As[wm + tm * 16 + lr][lq * 8];
#pragma unroll
        for (int tn = 0; tn < 2; tn++) {
            bg[tn] = *(const bf16x8*)&Bs[0][wn + tn * 16 + lr][lq * 8];
            bu[tn] = *(const bf16x8*)&Bs[1][wn + tn * 16 + lr][lq * 8];
        }
#pragma unroll
        for (int tm = 0; tm < 4; tm++)
#pragma unroll
            for (int tn = 0; tn < 2; tn++) {
                accg[tm][tn] = __builtin_amdgcn_mfma_f32_16x16x32_bf16(af[tm], bg[tn], accg[tm][tn], 0, 0, 0);
                accu[tm][tn] = __builtin_amdgcn_mfma_f32_16x16x32_bf16(af[tm], bu[tn], accu[tm][tn], 0, 0, 0);
            }
        __syncthreads();
    }

    // epilogue: h = silu(g)*u -> bf16, scattered by pair id
#pragma unroll
    for (int tm = 0; tm < 4; tm++)
#pragma unroll
        for (int tn = 0; tn < 2; tn++)
#pragma unroll
            for (int r = 0; r < 4; r++) {
                const int rowL = wm + tm * 16 + lq * 4 + r;   // C/D: row=(lane>>4)*4+reg
                const int slot = m0 + rowL;
                if (slot < ne) {
                    const int p = rowp[rowL];
                    const int col = n0 + wn + tn * 16 + lr;   // C/D: col=lane&15
                    const float g = accg[tm][tn][r];
                    const float u = accu[tm][tn][r];
                    const float hv = g * u / (1.f + __expf(-g));
                    hbuf[(size_t)p * INTER + col] = (unsigned short)bfround(hv);
                }
            }
}

// ---------------- gemm2: out[t] += w * (h_e @ Wd[e]) ----------------
// grid: (HIDDEN/64, TOKENS/128, NEXP), block 256
__global__ __launch_bounds__(256) void gemm2_kernel(
    const unsigned short* __restrict__ hbuf, const float* __restrict__ wdp,
    const int* __restrict__ cnt, const int* __restrict__ tok,
    const float* __restrict__ wts, float* __restrict__ out)
{
    const int e = blockIdx.z;
    const int ne = cnt[e];
    const int m0 = blockIdx.y * 128;
    if (m0 >= ne) return;
    const int n0 = blockIdx.x * 64;

    __shared__ __align__(16) unsigned short As[128][LDA];
    __shared__ __align__(16) unsigned short Bs[64][LDA];
    __shared__ int rowp[128];
    __shared__ float roww[128];

    const int tid = threadIdx.x;
    if (tid < 128) {
        const int slot = m0 + tid;
        const int cs = slot < ne ? slot : ne - 1;
        rowp[tid] = tok[e * TOKENS + cs];
        roww[tid] = wts[e * TOKENS + cs];
    }
    __syncthreads();

    const int lane = tid & 63;
    const int wid  = tid >> 6;
    const int wm = (wid >> 1) * 64;
    const int wn = (wid & 1) * 32;
    const int lr = lane & 15;
    const int lq = lane >> 4;

    f32x4 acc[4][2];
    const f32x4 z4 = {0.f, 0.f, 0.f, 0.f};
#pragma unroll
    for (int a = 0; a < 4; a++)
#pragma unroll
        for (int b = 0; b < 2; b++) acc[a][b] = z4;

    const float* wdq = wdp + (size_t)e * INTER * HIDDEN + n0;

    const int arow = tid >> 2;        // 0..63
    const int ac8  = (tid & 3) * 8;   // 0,8,16,24
    int ap[2];
    ap[0] = rowp[arow];
    ap[1] = rowp[arow + 64];

    for (int k0 = 0; k0 < INTER; k0 += 32) {
        // stage A (bf16 h rows, direct 16B copies)
#pragma unroll
        for (int i = 0; i < 2; i++) {
            const uint4 v = *(const uint4*)(hbuf + (size_t)ap[i] * INTER + k0 + ac8);
            *(uint4*)&As[arow + i * 64][ac8] = v;
        }
        // stage B transposed [n][k]
#pragma unroll
        for (int i = 0; i < 2; i++) {
            const int sid = (i << 8) + tid;
            const int kg = sid >> 6;
            const int n  = sid & 63;
            const float* src = wdq + (size_t)(k0 + kg * 4) * HIDDEN + n;
            uint2 pv;
            pv.x = pack2(src[0], src[(size_t)HIDDEN]);
            pv.y = pack2(src[2 * (size_t)HIDDEN], src[3 * (size_t)HIDDEN]);
            *(uint2*)&Bs[n][kg * 4] = pv;
        }
        __syncthreads();

        bf16x8 af[4], bb[2];
#pragma unroll
        for (int tm = 0; tm < 4; tm++)
            af[tm] = *(const bf16x8*)&As[wm + tm * 16 + lr][lq * 8];
#pragma unroll
        for (int tn = 0; tn < 2; tn++)
            bb[tn] = *(const bf16x8*)&Bs[wn + tn * 16 + lr][lq * 8];
#pragma unroll
        for (int tm = 0; tm < 4; tm++)
#pragma unroll
            for (int tn = 0; tn < 2; tn++)
                acc[tm][tn] = __builtin_amdgcn_mfma_f32_16x16x32_bf16(af[tm], bb[tn], acc[tm][tn], 0, 0, 0);
        __syncthreads();
    }

#pragma unroll
    for (int tm = 0; tm < 4; tm++)
#pragma unroll
        for (int tn = 0; tn < 2; tn++)
#pragma unroll
            for (int r = 0; r < 4; r++) {
                const int rowL = wm + tm * 16 + lq * 4 + r;
                const int slot = m0 + rowL;
                if (slot < ne) {
                    const int t = rowp[rowL] >> 1;
                    const float w = roww[rowL];
                    atomicAdd(&out[(size_t)t * HIDDEN + n0 + wn + tn * 16 + lr],
                              w * acc[tm][tn][r]);
                }
            }
}

extern "C" void kernel_launch(void* const* d_in, const int* in_sizes, int n_in,
                              void* d_out, int out_size, void* d_ws, size_t ws_size,
                              hipStream_t stream) {
    const float* x   = (const float*)d_in[0];
    const float* wg  = (const float*)d_in[1];
    const float* wgp = (const float*)d_in[2];
    const float* wup = (const float*)d_in[3];
    const float* wdp = (const float*)d_in[4];
    float* out = (float*)d_out;

    char* ws = (char*)d_ws;
    int*   cnt  = (int*)ws;                              // 64 B (aligned region 256)
    int*   tok  = (int*)(ws + 256);                      // 16*2048*4 = 131072
    float* wts  = (float*)(ws + 256 + 131072);           // 131072
    unsigned short* hbuf = (unsigned short*)(ws + 256 + 2 * 131072);  // 4096*1408*2 = 11.5 MB

    hipMemsetAsync(cnt, 0, NEXP * sizeof(int), stream);
    hipMemsetAsync(out, 0, (size_t)TOKENS * HIDDEN * sizeof(float), stream);

    router_kernel<<<dim3(TOKENS), dim3(64), 0, stream>>>(x, wg, cnt, tok, wts);

    dim3 g1(INTER / 64, TOKENS / 128, NEXP);    // (22, 16, 16), early-exit on cnt
    gemm1_kernel<<<g1, dim3(256), 0, stream>>>(x, wgp, wup, cnt, tok, hbuf);

    dim3 g2(HIDDEN / 64, TOKENS / 128, NEXP);   // (32, 16, 16)
    gemm2_kernel<<<g2, dim3(256), 0, stream>>>(hbuf, wdp, cnt, tok, wts, out);
}